// Round 10
// baseline (238.569 us; speedup 1.0000x reference)
//
#include <hip/hip_runtime.h>
#include <hip/hip_bf16.h>
#include <hip/hip_fp16.h>

#define NPOINTS 2048
#define BATCH   2
#define DIM     256
#define D2      128
#define D4      64
#define NHEAD   8
#define HDIM    32
#define KNNK    64
#define NROWS   (BATCH*NPOINTS)
#define SCALE_F 0.17677669529663687f

// pre_kernel block ranges
#define PRE_PREP   1568
#define PRE_PREP2  (PRE_PREP + 129)
#define PRE_QPROJ  (PRE_PREP2 + 256)
#define PRE_TOTAL  (PRE_QPROJ + NROWS)

typedef unsigned short u16;
typedef _Float16 f16x8 __attribute__((ext_vector_type(8)));
typedef float f32x4 __attribute__((ext_vector_type(4)));

__device__ __forceinline__ u16 f2h(float f) {
  __half h = __float2half(f); u16 r; __builtin_memcpy(&r, &h, 2); return r;
}
__device__ __forceinline__ unsigned pkh2(float a, float b) {
  __half2 h = __floats2half2_rn(a, b); unsigned r; __builtin_memcpy(&r, &h, 4); return r;
}
__device__ __forceinline__ float2 uph2(unsigned u) {
  __half2 h; __builtin_memcpy(&h, &u, 4); return __half22float2(h);
}

#if __has_builtin(__builtin_amdgcn_fdot2)
typedef _Float16 hv2_t __attribute__((ext_vector_type(2)));
__device__ __forceinline__ float fdot2f(unsigned a, unsigned b, float c) {
  hv2_t x, y; __builtin_memcpy(&x, &a, 4); __builtin_memcpy(&y, &b, 4);
  return __builtin_amdgcn_fdot2(x, y, c, false);
}
#else
__device__ __forceinline__ float fdot2f(unsigned a, unsigned b, float c) {
  float2 x = uph2(a), y = uph2(b);
  return fmaf(x.x, y.x, fmaf(x.y, y.y, c));
}
#endif

// MFMA helper: acc[4] (+)= A(16x256 f32 rows in LDS, stride ldsA) @ Bfrag,
// wave w owns n-tiles 4w..4w+3.  Fragment scheme identical to the verified
// h2-GEMM: A lane l holds A[m=l&15][k=ks*32+(l>>4)*8+e]; B packed with the
// same (l,e)->k bijection; D: col=lane&15, row=(lane>>4)*4+reg.
__device__ __forceinline__ void mfma_gemm_acc(
    const float* A, int ldsA, const u16* __restrict__ bfrag,
    int w, int l, f32x4 acc[4])
{
  const int lm = l & 15, lg = l >> 4;
  #pragma unroll
  for (int ks = 0; ks < 8; ++ks) {
    const float* ar = A + lm*ldsA + ks*32 + lg*8;
    float4 a0 = *(const float4*)ar;
    float4 a1 = *(const float4*)(ar + 4);
    f16x8 af;
    af[0]=(_Float16)a0.x; af[1]=(_Float16)a0.y; af[2]=(_Float16)a0.z; af[3]=(_Float16)a0.w;
    af[4]=(_Float16)a1.x; af[5]=(_Float16)a1.y; af[6]=(_Float16)a1.z; af[7]=(_Float16)a1.w;
    #pragma unroll
    for (int ni = 0; ni < 4; ++ni) {
      const int n = w*4 + ni;
      f16x8 bf;
      uint4 bv = *(const uint4*)(bfrag + (((n*8 + ks)*64 + l) << 3));
      __builtin_memcpy(&bf, &bv, 16);
      acc[ni] = __builtin_amdgcn_mfma_f32_16x16x32_f16(af, bf, acc[ni], 0, 0, 0);
    }
  }
}

// ---------------------------------------------------------------------------
// Mega pre-kernel: prep | prep2 | qproj | knn, dispatched by block range.
// ---------------------------------------------------------------------------
__global__ __launch_bounds__(256) void pre_kernel(
    const float* __restrict__ xyz,
    u16*    __restrict__ knn_idx,
    __half* __restrict__ knn_dist,
    const float* __restrict__ wk, const float* __restrict__ wv,
    const float* __restrict__ de_w2,
    u16* __restrict__ wkT2, u16* __restrict__ wvB2, u16* __restrict__ w2frag,
    const float* __restrict__ de_w3, const float* __restrict__ de_b3,
    const float* __restrict__ bk, const float* __restrict__ bv,
    u16* __restrict__ w3kp, u16* __restrict__ w3vp,
    unsigned* __restrict__ bkb3kp, float* __restrict__ cbias,
    const float* __restrict__ features, const float* __restrict__ wq,
    const float* __restrict__ bq, float* __restrict__ qout,
    const float* __restrict__ wo, const float* __restrict__ se_w1,
    const float* __restrict__ se_w2,
    u16* __restrict__ wofrag, u16* __restrict__ w1afrag,
    u16* __restrict__ w1bfrag, u16* __restrict__ w2ffrag)
{
  __shared__ __align__(16) char pmem[16648];
  const int blk = blockIdx.x;
  const int t = threadIdx.x;

  if (blk < PRE_PREP) {
    // ---------------- prep: f16 repacks + MFMA fragment packs ----------------
    int tid = blk*256 + t;
    if (tid < 65536) {
      int d = tid >> 8, c = tid & 255;
      wkT2[(d>>1)*512 + c*2 + (d&1)] = f2h(wk[c*DIM + d]);
    } else if (tid < 131072) {
      int o = tid - 65536; int c = o >> 8, d = o & 255;
      wvB2[(c>>1)*512 + d*2 + (c&1)] = f2h(wv[c*DIM + d]);
    } else if (tid < 139264) {
      int o = tid - 131072;
      int e = o & 7, l = (o >> 3) & 63, ks = (o >> 9) & 1, n = o >> 10;
      int i = ks*32 + ((l >> 4) << 3) + e;
      int j = n*16 + (l & 15);
      w2frag[o] = f2h(de_w2[i*D2 + j]);
    } else if (tid < 401408) {
      int o = (tid - 139264) & 65535;
      int sel = (tid - 139264) >> 16;          // 0:wo 1:w1a 2:w1b 3:w2
      int e = o & 7, l = (o >> 3) & 63, ks = (o >> 9) & 7, n = o >> 12;
      int i = ks*32 + ((l >> 4) << 3) + e;
      int j = n*16 + (l & 15);
      if      (sel == 0) wofrag[o]  = f2h(wo[i*DIM + j]);
      else if (sel == 1) w1afrag[o] = f2h(se_w1[i*DIM + j]);
      else if (sel == 2) w1bfrag[o] = f2h(se_w1[(DIM + i)*DIM + j]);
      else               w2ffrag[o] = f2h(se_w2[i*DIM + j]);
    }
    return;
  }
  if (blk < PRE_PREP2) {
    // ---------------- prep2: weight-fold GEMMs ----------------
    const int j = blk - PRE_PREP;
    float ak = 0.f, av = 0.f;
    if (j < D2) {
      const float* wrow = de_w3 + (size_t)j*DIM;
      #pragma unroll 4
      for (int c = 0; c < DIM; ++c) {
        float w = wrow[c];
        ak = fmaf(w, wk[c*DIM + t], ak);
        av = fmaf(w, wv[c*DIM + t], av);
      }
      w3kp[(((t>>5)*D2 + j)<<5) + (t&31)] = f2h(ak);
      w3vp[(j>>1)*512 + t*2 + (j&1)]      = f2h(av);
    } else {
      #pragma unroll 4
      for (int c = 0; c < DIM; ++c) {
        float w = de_b3[c];
        ak = fmaf(w, wk[c*DIM + t], ak);
        av = fmaf(w, wv[c*DIM + t], av);
      }
      float vb = bk[t] + ak;
      float vbn = __shfl_down(vb, 1);
      if ((t & 1) == 0) bkb3kp[t >> 1] = pkh2(vb, vbn);
      cbias[t] = bv[t] + av;
    }
    return;
  }
  if (blk < PRE_QPROJ) {
    // ---------------- qproj: 16 rows/block; emits q as f16 PAIRS ----------
    float (*sf)[DIM] = (float (*)[DIM])pmem;
    const int r0 = (blk - PRE_PREP2) * 16;
    for (int r = 0; r < 16; ++r) sf[r][t] = features[(size_t)(r0+r)*DIM + t];
    __syncthreads();
    float acc[16];
    const float bqv = bq[t];
    #pragma unroll
    for (int r = 0; r < 16; ++r) acc[r] = bqv;
    for (int d = 0; d < DIM; d += 4) {
      float w0 = wq[(d+0)*DIM+t], w1 = wq[(d+1)*DIM+t];
      float w2 = wq[(d+2)*DIM+t], w3v = wq[(d+3)*DIM+t];
      #pragma unroll
      for (int r = 0; r < 16; ++r) {
        float4 f4 = *(const float4*)&sf[r][d];
        acc[r] = fmaf(f4.x, w0, acc[r]); acc[r] = fmaf(f4.y, w1, acc[r]);
        acc[r] = fmaf(f4.z, w2, acc[r]); acc[r] = fmaf(f4.w, w3v, acc[r]);
      }
    }
    __syncthreads();           // sf (features) dead
    #pragma unroll
    for (int r = 0; r < 16; ++r) sf[r][t] = acc[r];
    __syncthreads();
    if (t < 128) {
      for (int r = 0; r < 16; ++r) {
        unsigned* qpo = (unsigned*)(qout + (size_t)(r0+r)*DIM);
        qpo[t] = pkh2(sf[r][2*t], sf[r][2*t+1]);
      }
    }
    return;
  }

  // ---------------- knn: exact 64-NN on squared distances ----------------
  {
    float*    dist = (float*)pmem;                 // 8KB (squared dists)
    unsigned* hist = (unsigned*)(pmem + 8192);     // 1KB
    unsigned* shw  = (unsigned*)(pmem + 9216);     // sel, below

    const int bp = blk - PRE_QPROJ;
    const int b  = bp >> 11;
    const int n  = bp & (NPOINTS - 1);
    const float* P = xyz + (size_t)b * NPOINTS * 3;

    const float qx = P[n*3+0], qy = P[n*3+1], qz = P[n*3+2];
    const float r2n = qx*qx + qy*qy + qz*qz;
    float dreg[8];
    #pragma unroll
    for (int g = 0; g < 8; ++g) {
      const int m = t + 256*g;
      float x = P[m*3+0], y = P[m*3+1], z = P[m*3+2];
      float r2m = x*x + y*y + z*z;
      float dt  = x*qx + y*qy + z*qz;
      float sq  = r2n + r2m - 2.f*dt;
      dreg[g] = fmaxf(sq, 0.f);     // sqrt deferred to the 64 outputs
      dist[m] = dreg[g];
    }
    __syncthreads();

    unsigned prefix = 0u;
    int k_need = KNNK;
    for (int pass = 0; pass < 4; ++pass) {
      const int shift = 24 - pass*8;
      hist[t] = 0u;
      __syncthreads();
      #pragma unroll
      for (int g = 0; g < 8; ++g) {
        unsigned bits = __float_as_uint(dreg[g]);
        if (((bits >> shift) >> 8) == prefix)
          atomicAdd(&hist[(bits >> shift) & 255u], 1u);
      }
      __syncthreads();
      if (t < 64) {
        unsigned s0 = hist[t*4+0], s1 = hist[t*4+1], s2 = hist[t*4+2], s3 = hist[t*4+3];
        unsigned lsum = s0 + s1 + s2 + s3;
        unsigned scan = lsum;
        #pragma unroll
        for (int off = 1; off < 64; off <<= 1) {
          unsigned o = __shfl_up(scan, off);
          if (t >= off) scan += o;
        }
        unsigned excl = scan - lsum;
        unsigned kk = (unsigned)k_need;
        if (excl < kk && kk <= excl + lsum) {
          unsigned below = excl; int bin = t*4;
          if (kk > below + s0) { below += s0; bin++;
            if (kk > below + s1) { below += s1; bin++;
              if (kk > below + s2) { below += s2; bin++; } } }
          shw[0] = (unsigned)bin; shw[1] = below;
        }
      }
      __syncthreads();
      prefix = (prefix << 8) | shw[0];
      k_need -= (int)shw[1];
      __syncthreads();
    }
    const unsigned Tbits = prefix;
    const int base = KNNK - k_need;

    if (t < 64) {
      u16*    oi = knn_idx  + (size_t)bp * KNNK;
      __half* od = knn_dist + (size_t)bp * KNNK;
      int taken = 0;
      for (int c = 0; c < NPOINTS/64; ++c) {
        int m = c*64 + t;
        float dv = dist[m];
        bool lt = (__float_as_uint(dv) < Tbits);
        unsigned long long msk = __ballot(lt);
        int off = __popcll(msk & ((1ull << t) - 1ull));
        if (lt) { oi[taken+off] = (u16)m; od[taken+off] = __float2half(sqrtf(dv)); }
        taken += __popcll(msk);
      }
      int eq = 0;
      for (int c = 0; c < NPOINTS/64 && eq < k_need; ++c) {
        int m = c*64 + t;
        float dv = dist[m];
        bool e = (__float_as_uint(dv) == Tbits);
        unsigned long long msk = __ballot(e);
        int off = __popcll(msk & ((1ull << t) - 1ull));
        if (e && (eq + off) < k_need) { oi[base+eq+off] = (u16)m; od[base+eq+off] = __float2half(sqrtf(dv)); }
        eq += __popcll(msk);
      }
    }
  }
}

// ---------------------------------------------------------------------------
// Fused per-point pipeline.  q-pairs staged in LDS (one-time, broadcast
// reads); mF with 4-deep static prefetch.  LDS 25632 B -> 6 blocks/CU.
// ---------------------------------------------------------------------------
__global__ __launch_bounds__(256, 6) void fused_kernel(
    const float* __restrict__ features,
    float* __restrict__ qctx,                       // d_out: qp in, ctx out
    const u16*    __restrict__ knn_idx,
    const __half* __restrict__ knn_dist,
    const u16* __restrict__ wkT2, const u16* __restrict__ wvB2,
    const u16* __restrict__ w2frag,
    const u16* __restrict__ w3kp, const u16* __restrict__ w3vp,
    const float* __restrict__ de_w1, const float* __restrict__ de_b1,
    const float* __restrict__ de_b2,
    const unsigned* __restrict__ bkb3kp, const float* __restrict__ cbias)
{
  // [0,16K)        s_h2  h2 f16 swizzled            phase1 -> P8a
  // [16K,20K)      gp u32[8][128] (phase1->P5') | mp u32[8][128] (P8a->P9')
  // [20K,22K)      w3gb f16[8][128] (phase1->P5') | aT f32[64][8] (P6->P8a/mF)
  // [22K,24K)      sc f32[8][64] (P5'->P6)       | ah2p u32[64][8] (P8a->P9')
  // [24K,25120)    nidx[64], ndist[64], sb[8]
  // [25120,25632)  s_qp u32[128]  (P0 -> phase1)
  __shared__ __align__(16) char smem[25632];
  unsigned* s_h2_32 = (unsigned*)(smem);
  unsigned* s_gp32  = (unsigned*)(smem + 16384);
  unsigned* s_mp32  = (unsigned*)(smem + 16384);
  u16*      s_w3gb  = (u16*)(smem + 20480);
  unsigned* s_w3g32 = (unsigned*)(smem + 20480);
  float*    s_aT    = (float*)(smem + 20480);
  float*    s_sc    = (float*)(smem + 22528);
  unsigned* s_ah2p  = (unsigned*)(smem + 22528);
  int*      s_nidx  = (int*)(smem + 24576);
  float*    s_ndist = (float*)(smem + 24832);
  float*    s_sb    = (float*)(smem + 25088);
  unsigned* s_qp    = (unsigned*)(smem + 25120);

  const int bp = blockIdx.x;
  const int b  = bp >> 11;
  const int t  = threadIdx.x;
  const float* featB = features + (size_t)b * NPOINTS * DIM;
  const unsigned* qpg = (const unsigned*)(qctx + (size_t)bp * DIM);

  // ---- P0 ----
  if (t < KNNK) {
    s_nidx[t]  = (int)knn_idx[(size_t)bp*KNNK + t];
    s_ndist[t] = __half2float(knn_dist[(size_t)bp*KNNK + t]);
  }
  if (t < 128) s_qp[t] = qpg[t];
  __syncthreads();

  // ================= phase 1 =================
  // g-fold: g[c=t][h] = sum_{d in h} wk[c][d] q[d]; linear [h][c] f16 layout.
  {
    const unsigned* wk2 = (const unsigned*)wkT2;
    u16* gps = (u16*)s_gp32;
    #pragma unroll
    for (int h = 0; h < NHEAD; ++h) {
      float a = 0.f;
      #pragma unroll
      for (int dg = 0; dg < 16; ++dg) {
        const int d2 = h*16 + dg;                  // uniform -> LDS broadcast
        a = fdot2f(wk2[d2*256 + t], s_qp[d2], a);
      }
      gps[h*256 + t] = f2h(a);
    }
  }
  // w3g-fold: w3g[h][j] = sum_{d in h} w3k[j][d] q[d]; linear [h][j] f16.
  {
    const int h = t >> 5, jj = t & 31;
    unsigned qph[16];
    #pragma unroll
    for (int dp = 0; dp < 16; ++dp) qph[dp] = s_qp[h*16 + dp];
    const unsigned* w3k32 = (const unsigned*)w3kp;
    #pragma unroll
    for (int r = 0; r < 4; ++r) {
      const int j = jj*4 + r;
      const uint4* wr = (const uint4*)(w3k32 + ((h*D2 + j)<<4));
      uint4 w0 = wr[0], w1 = wr[1], w2 = wr[2], w3 = wr[3];
      float a = 0.f;
      a = fdot2f(w0.x,qph[0],a);  a = fdot2f(w0.y,qph[1],a);
      a = fdot2f(w0.z,qph[2],a);  a = fdot2f(w0.w,qph[3],a);
      a = fdot2f(w1.x,qph[4],a);  a = fdot2f(w1.y,qph[5],a);
      a = fdot2f(w1.z,qph[6],a);  a = fdot2f(w1.w,qph[7],a);
      a = fdot2f(w2.x,qph[8],a);  a = fdot2f(w2.y,qph[9],a);
      a = fdot2f(w2.z,qph[10],a); a = fdot2f(w2.w,qph[11],a);
      a = fdot2f(w3.x,qph[12],a); a = fdot2f(w3.y,qph[13],a);
      a = fdot2f(w3.z,qph[14],a); a = fdot2f(w3.w,qph[15],a);
      s_w3gb[h*D2 + j] = f2h(a);
    }
  }
  if (t < NHEAD) {
    float s = 0.f;
    #pragma unroll
    for (int dp = 0; dp < 16; ++dp)
      s = fdot2f(bkb3kp[t*16 + dp], s_qp[t*16 + dp], s);
    s_sb[t] = s;
  }
  // h2 = relu(h1 @ w2 + b2) via MFMA; wave w owns n in {2w,2w+1} for all kk.
  {
    const int w = t >> 6, l = t & 63;
    const int lm = l & 15, lg = l >> 4;
    f16x8 af[4][2];
    #pragma unroll
    for (int ks = 0; ks < 2; ++ks) {
      const int i0 = ks*32 + lg*8;
      float4 w1a = *(const float4*)&de_w1[i0];
      float4 w1b = *(const float4*)&de_w1[i0+4];
      float4 b1a = *(const float4*)&de_b1[i0];
      float4 b1b = *(const float4*)&de_b1[i0+4];
      #pragma unroll
      for (int kt = 0; kt < 4; ++kt) {
        const float dd = s_ndist[kt*16 + lm];
        af[kt][ks][0] = (_Float16)fmaxf(fmaf(dd, w1a.x, b1a.x), 0.f);
        af[kt][ks][1] = (_Float16)fmaxf(fmaf(dd, w1a.y, b1a.y), 0.f);
        af[kt][ks][2] = (_Float16)fmaxf(fmaf(dd, w1a.z, b1a.z), 0.f);
        af[kt][ks][3] = (_Float16)fmaxf(fmaf(dd, w1a.w, b1a.w), 0.f);
        af[kt][ks][4] = (_Float16)fmaxf(fmaf(dd, w1b.x, b1b.x), 0.f);
        af[kt][ks][5] = (_Float16)fmaxf(fmaf(dd, w1b.y, b1b.y), 0.f);
        af[kt][ks][6] = (_Float16)fmaxf(fmaf(dd, w1b.z, b1b.z), 0.f);
        af[kt][ks][7] = (_Float16)fmaxf(fmaf(dd, w1b.w, b1b.w), 0.f);
      }
    }
    u16* h2w = (u16*)s_h2_32;
    #pragma unroll
    for (int ni = 0; ni < 2; ++ni) {
      const int n = 2*w + ni;
      const int j = n*16 + lm;
      f16x8 bf0, bf1;
      uint4 r0 = *(const uint4*)(w2frag + (((n*2+0)*64 + l)<<3));
      uint4 r1 = *(const uint4*)(w2frag + (((n*2+1)*64 + l)<<3));
      __builtin_memcpy(&bf0, &r0, 16);
      __builtin_memcpy(&bf1, &r1, 16);
      const float b2j = de_b2[j];
      #pragma unroll
      for (int kt = 0; kt < 4; ++kt) {
        f32x4 c = {b2j, b2j, b2j, b2j};
        c = __builtin_amdgcn_mfma_f32_16x16x32_f16(af[kt][0], bf0, c, 0, 0, 0);
        c = __builtin_amdgcn_mfma_f32_16x16x32_f16(af[kt][1], bf1, c, 0, 0, 0);
        #pragma unroll
        for (int r = 0; r < 4; ++r) {
          const int kk = kt*16 + lg*4 + r;
          h2w[kk*128 + (((j>>3)^(kk&15))<<3) + (j&7)] = f2h(fmaxf(c[r], 0.f));
        }
      }
    }
  }
  __syncthreads();

  // ================= P5': scores =================
  {
    const int kk = t >> 2, sub = t & 3;
    const int kb = kk & 15;
    const float* Fr = featB + (size_t)s_nidx[kk]*DIM;
    float part[8];
    #pragma unroll
    for (int h = 0; h < 8; ++h) part[h] = 0.f;
    #pragma unroll 2
    for (int j = 0; j < 8; ++j) {
      const int c0 = (j*4 + sub)*8;
      float4 fA = *(const float4*)&Fr[c0];
      float4 fB = *(const float4*)&Fr[c0+4];
      unsigned p0 = pkh2(fA.x, fA.y), p1 = pkh2(fA.z, fA.w);
      unsigned p2 = pkh2(fB.x, fB.y), p3 = pkh2(fB.z, fB.w);
      #pragma unroll
      for (int h = 0; h < 8; ++h) {
        uint4 g = *(const uint4*)(s_gp32 + h*128 + (j*4 + sub)*4);
        float a = part[h];
        a = fdot2f(p0, g.x, a); a = fdot2f(p1, g.y, a);
        a = fdot2f(p2, g.z, a); a = fdot2f(p3, g.w, a);
        part[h] = a;
      }
    }
    uint4 h2v[4];
    #pragma unroll
    for (int i = 0; i < 4; ++i)
      h2v[i] = *(const uint4*)(s_h2_32 + kk*64 + ((((sub<<2)+i) ^ kb) << 2));
    #pragma unroll
    for (int h = 0; h < 8; ++h) {
      const uint4* wg = (const uint4*)(s_w3g32 + h*64 + sub*16);
      float a = part[h];
      #pragma unroll
      for (int i = 0; i < 4; ++i) {
        uint4 w = wg[i];
        a = fdot2f(h2v[i].x, w.x, a); a = fdot2f(h2v[i].y, w.y, a);
        a = fdot2f(h2v[i].z, w.z, a); a = fdot2f(h2v[i].w, w.w, a);
      }
      part[h] = a;
    }
    #pragma unroll
    for (int h = 0; h < 8; ++h) {
      part[h] += __shfl_xor(part[h], 1);
      part[h] += __shfl_xor(part[h], 2);
    }
    const int h0 = sub*2;
    s_sc[h0*64 + kk]     = (part[h0]   + s_sb[h0])   * SCALE_F;
    s_sc[(h0+1)*64 + kk] = (part[h0+1] + s_sb[h0+1]) * SCALE_F;
  }
  __syncthreads();

  // ================= P6: softmax =================
  {
    const int h = t >> 5, k2 = t & 31;
    float v0 = s_sc[h*64 + k2], v1 = s_sc[h*64 + k2 + 32];
    float mx = fmaxf(v0, v1);
    #pragma unroll
    for (int off = 16; off > 0; off >>= 1) mx = fmaxf(mx, __shfl_xor(mx, off, 32));
    float e0 = expf(v0 - mx), e1 = expf(v1 - mx);
    float sm = e0 + e1;
    #pragma unroll
    for (int off = 16; off > 0; off >>= 1) sm += __shfl_xor(sm, off, 32);
    float inv = 1.f / sm;
    s_aT[k2*NHEAD + h]      = e0 * inv;
    s_aT[(k2+32)*NHEAD + h] = e1 * inv;
  }
  __syncthreads();

  // ================= P8a: ah2 = attn @ h2 ; mF = attn @ F =================
  {
    const int jj2 = t & 63, hp = t >> 6;
    const int j = jj2*2;
    float a00=0.f, a01=0.f, a10=0.f, a11=0.f;
    #pragma unroll 8
    for (int kk = 0; kk < KNNK; ++kk) {
      unsigned hpw = s_h2_32[kk*64 + (((j>>3)^(kk&15))<<2) + ((j&7)>>1)];
      float2 hv = uph2(hpw);
      float2 av = *(const float2*)&s_aT[kk*NHEAD + hp*2];
      a00 = fmaf(av.x, hv.x, a00); a01 = fmaf(av.x, hv.y, a01);
      a10 = fmaf(av.y, hv.x, a10); a11 = fmaf(av.y, hv.y, a11);
    }
    s_ah2p[jj2*8 + hp*2]     = pkh2(a00, a01);
    s_ah2p[jj2*8 + hp*2 + 1] = pkh2(a10, a11);
  }
  // mF c-split per wave; each F row read once per block (broadcast lanes);
  // 4-deep static prefetch to cover L2 latency.
  {
    const int w = t >> 6, l = t & 63;
    const int h = l >> 3, c8 = l & 7;
    const int coff = w*64 + c8*8;
    float mac[8];
    #pragma unroll
    for (int i = 0; i < 8; ++i) mac[i] = 0.f;
    float4 fa0, fb0, fa1, fb1, fa2, fb2, fa3, fb3;
    {
      const float* F0 = featB + (size_t)s_nidx[0]*DIM + coff;
      const float* F1 = featB + (size_t)s_nidx[1]*DIM + coff;
      const float* F2 = featB + (size_t)s_nidx[2]*DIM + coff;
      const float* F3 = featB + (size_t)s_nidx[3]*DIM + coff;
      fa0 = *(const float4*)F0; fb0 = *(const float4*)(F0+4);
      fa1 = *(const float4*)F1; fb1 = *(const float4*)(F1+4);
      fa2 = *(const float4*)F2; fb2 = *(const float4*)(F2+4);
      fa3 = *(const float4*)F3; fb3 = *(const float4*)(F3+4);
    }
    for (int kk = 0; kk < KNNK; kk += 4) {
      float4 ca0=fa0, cb0=fb0, ca1=fa1, cb1=fb1;
      float4 ca2=fa2, cb2=fb2, ca3=fa3, cb3=fb3;
      if (kk + 4 < KNNK) {
        const float* F0 = featB + (size_t)s_nidx[kk+4]*DIM + coff;
        const float* F1 = featB + (size_t)s_nidx[kk+5]*DIM + coff;
        const float* F2 = featB + (size_t)s_nidx[kk+6]*DIM + coff;
        const float* F3 = featB + (size_t)s_nidx[kk+7]*DIM + coff;
        fa0 = *(const float4*)F0; fb0 = *(const float4*)(F0+4);
        fa1 = *(const float4*)F1; fb1 = *(const float4*)(F1+4);
        fa2 = *(const float4*)F2; fb2 = *(const float4*)(F2+4);
        fa3 = *(const float4*)F3; fb3 = *(const float4*)(F3+4);
      }
      float a0 = s_aT[(kk+0)*NHEAD + h];
      float a1 = s_aT[(kk+1)*NHEAD + h];
      float a2 = s_aT[(kk+2)*NHEAD + h];
      float a3 = s_aT[(kk+3)*NHEAD + h];
      mac[0] = fmaf(a0, ca0.x, mac[0]); mac[1] = fmaf(a0, ca0.y, mac[1]);
      mac[2] = fmaf(a0, ca0.z, mac[2]); mac[3] = fmaf(a0, ca0.w, mac[3]);
      mac[4] = fmaf(a0, cb0.x, mac[4]); mac[5] = fmaf(a0, cb0.y, mac[5]);
      mac[6] = fmaf(a0, cb0.z, mac[6]); mac[7] = fmaf(a0, cb0.w, mac[7]);
      mac[0] = fmaf(a1, ca1.x, mac[0]); mac[1] = fmaf(a1, ca1.y, mac[1]);
      mac[2] = fmaf(a1, ca1.z, mac[2]); mac[3] = fmaf(a1, ca1.w, mac[3]);
      mac[4] = fmaf(a1, cb1.x, mac[4]); mac[5] = fmaf(a1, cb1.y, mac[5]);
      mac[6] = fmaf(a1, cb1.z, mac[6]); mac[7] = fmaf(a1, cb1.w, mac[7]);
      mac[0] = fmaf(a2, ca2.x, mac[0]); mac[1] = fmaf(a2, ca2.y, mac[1]);
      mac[2] = fmaf(a2, ca2.z, mac[2]); mac[3] = fmaf(a2, ca2.w, mac[3]);
      mac[4] = fmaf(a2, cb2.x, mac[4]); mac[5] = fmaf(a2, cb2.y, mac[5]);
      mac[6] = fmaf(a2, cb2.z, mac[6]); mac[7] = fmaf(a2, cb2.w, mac[7]);
      mac[0] = fmaf(a3, ca3.x, mac[0]); mac[1] = fmaf(a3, ca3.y, mac[1]);
      mac[2] = fmaf(a3, ca3.z, mac[2]); mac[3] = fmaf(a3, ca3.w, mac[3]);
      mac[4] = fmaf(a3, cb3.x, mac[4]); mac[5] = fmaf(a3, cb3.y, mac[5]);
      mac[6] = fmaf(a3, cb3.z, mac[6]); mac[7] = fmaf(a3, cb3.w, mac[7]);
    }
    *(uint4*)(s_mp32 + h*128 + (coff >> 1)) =
        make_uint4(pkh2(mac[0], mac[1]), pkh2(mac[2], mac[3]),
                   pkh2(mac[4], mac[5]), pkh2(mac[6], mac[7]));
  }
  __syncthreads();

  // ================= P9': ctx = mF.wv + ah2.w3v + cb (all fdot2) ==========
  {
    const int h = t >> 5;
    const unsigned* mr = s_mp32 + h*128;
    const unsigned* wv32 = (const unsigned*)wvB2;
    float acc = cbias[t];
    #pragma unroll 4
    for (int c2 = 0; c2 < 128; ++c2)
      acc = fdot2f(mr[c2], wv32[c2*256 + t], acc);
    const unsigned* w3v32 = (const unsigned*)w3vp;
    #pragma unroll 4
    for (int j2 = 0; j2 < 64; ++j2)
      acc = fdot2f(s_ah2p[j2*8 + h], w3v32[j2*256 + t], acc);
    qctx[(size_t)bp*DIM + t] = acc;
  }
}

// ---------------------------------------------------------------------------
// Batched tail on MFMA: 16 rows/block, 4 GEMMs via prepacked B-fragments.
// ---------------------------------------------------------------------------
__global__ __launch_bounds__(256) void se_kernel(
    const float* __restrict__ features,
    const u16* __restrict__ wofrag,  const u16* __restrict__ w1afrag,
    const u16* __restrict__ w1bfrag, const u16* __restrict__ w2ffrag,
    const float* __restrict__ bo,    const float* __restrict__ se_b1,
    const float* __restrict__ ln_g,  const float* __restrict__ ln_b,
    const float* __restrict__ se_b2,
    float* io)
{
  __shared__ __align__(16) float sC[16][260];   // ctx -> x
  __shared__ __align__(16) float sF[16][260];   // feat -> rx
  __shared__ __align__(16) float sX[16][260];   // att
  __shared__ float s_mu[16], s_rs[16];
  const int r0 = blockIdx.x * 16, t = threadIdx.x;
  const int w = t >> 6, l = t & 63, lm = l & 15, lg = l >> 4;

  for (int r = 0; r < 16; ++r) {
    sC[r][t] = io[(size_t)(r0+r)*DIM + t];
    sF[r][t] = features[(size_t)(r0+r)*DIM + t];
  }
  __syncthreads();

  // GEMM1: att = ctx @ wo + bo -> sX
  {
    f32x4 acc[4];
    #pragma unroll
    for (int ni = 0; ni < 4; ++ni) {
      float bb = bo[(w*4+ni)*16 + lm];
      acc[ni] = (f32x4){bb, bb, bb, bb};
    }
    mfma_gemm_acc(&sC[0][0], 260, wofrag, w, l, acc);
    #pragma unroll
    for (int ni = 0; ni < 4; ++ni)
      #pragma unroll
      for (int r = 0; r < 4; ++r)
        sX[lg*4+r][(w*4+ni)*16 + lm] = acc[ni][r];
  }
  __syncthreads();   // sX ready; all sC (ctx) reads complete

  // GEMM2: x = feat@w1a + att@w1b + b1 -> sC
  {
    f32x4 acc[4];
    #pragma unroll
    for (int ni = 0; ni < 4; ++ni) {
      float bb = se_b1[(w*4+ni)*16 + lm];
      acc[ni] = (f32x4){bb, bb, bb, bb};
    }
    mfma_gemm_acc(&sF[0][0], 260, w1afrag, w, l, acc);
    mfma_gemm_acc(&sX[0][0], 260, w1bfrag, w, l, acc);
    #pragma unroll
    for (int ni = 0; ni < 4; ++ni)
      #pragma unroll
      for (int r = 0; r < 4; ++r)
        sC[lg*4+r][(w*4+ni)*16 + lm] = acc[ni][r];
  }
  __syncthreads();

  // LayerNorm stats (4 rows per wave)
  {
    const int lane = t & 63;
    for (int i = 0; i < 4; ++i) {
      const int r = w*4 + i;
      float v0 = sC[r][lane], v1 = sC[r][lane+64];
      float v2 = sC[r][lane+128], v3 = sC[r][lane+192];
      float s1 = v0+v1+v2+v3;
      float s2 = v0*v0 + v1*v1 + v2*v2 + v3*v3;
      #pragma unroll
      for (int off = 32; off > 0; off >>= 1) {
        s1 += __shfl_xor(s1, off);
        s2 += __shfl_xor(s2, off);
      }
      if (lane == 0) {
        float mu = s1 * (1.f/256.f);
        s_mu[r] = mu;
        s_rs[r] = 1.f / sqrtf(s2 * (1.f/256.f) - mu*mu + 1e-5f);
      }
    }
  }
  __syncthreads();

  // rx = relu(LN(x)) -> sF (feat dead)
  {
    const float lg2 = ln_g[t], lb2 = ln_b[t];
    #pragma unroll
    for (int r = 0; r < 16; ++r)
      sF[r][t] = fmaxf(fmaf((sC[r][t] - s_mu[r]) * s_rs[r], lg2, lb2), 0.f);
  }
  __syncthreads();

  // GEMM3: out = rx @ se_w2 + b2 -> io
  {
    f32x4 acc[4];
    #pragma unroll
    for (int ni = 0; ni < 4; ++ni) {
      float bb = se_b2[(w*4+ni)*16 + lm];
      acc[ni] = (f32x4){bb, bb, bb, bb};
    }
    mfma_gemm_acc(&sF[0][0], 260, w2ffrag, w, l, acc);
    #pragma unroll
    for (int ni = 0; ni < 4; ++ni)
      #pragma unroll
      for (int r = 0; r < 4; ++r)
        io[(size_t)(r0 + lg*4 + r)*DIM + (w*4+ni)*16 + lm] = acc[ni][r];
  }
}

extern "C" void kernel_launch(void* const* d_in, const int* in_sizes, int n_in,
                              void* d_out, int out_size, void* d_ws, size_t ws_size,
                              hipStream_t stream) {
  const float* features = (const float*)d_in[0];
  const float* xyz      = (const float*)d_in[1];
  const float* de_w1 = (const float*)d_in[2];
  const float* de_b1 = (const float*)d_in[3];
  const float* de_w2 = (const float*)d_in[4];
  const float* de_b2 = (const float*)d_in[5];
  const float* de_w3 = (const float*)d_in[6];
  const float* de_b3 = (const float*)d_in[7];
  const float* wq = (const float*)d_in[8];
  const float* bq = (const float*)d_in[9];
  const float* wk = (const float*)d_in[10];
  const float* bk = (const float*)d_in[11];
  const float* wv = (const float*)d_in[12];
  const float* bv = (const float*)d_in[13];
  const float* wo = (const float*)d_in[14];
  const float* bo = (const float*)d_in[15];
  const float* se_w1 = (const float*)d_in[16];
  const float* se_b1 = (const float*)d_in[17];
  const float* ln_g  = (const float*)d_in[18];
  const float* ln_b  = (const float*)d_in[19];
  const float* se_w2 = (const float*)d_in[20];
  const float* se_b2 = (const float*)d_in[21];

  // ws layout (1984000 B < 2 MB):
  char* wsb = (char*)d_ws;
  u16*    knn_idx  = (u16*)wsb;
  __half* knn_dist = (__half*)(wsb + 524288u);
  u16*      wkT2    = (u16*)(wsb + 1048576u);
  u16*      wvB2    = (u16*)(wsb + 1179648u);
  u16*      w2frag  = (u16*)(wsb + 1310720u);
  u16*      w3kp    = (u16*)(wsb + 1327104u);
  u16*      w3vp    = (u16*)(wsb + 1392640u);
  unsigned* bkb3kp  = (unsigned*)(wsb + 1458176u);
  float*    cbias   = (float*)(wsb + 1458688u);
  u16*      wofrag  = (u16*)(wsb + 1459712u);
  u16*      w1afrag = (u16*)(wsb + 1590784u);
  u16*      w1bfrag = (u16*)(wsb + 1721856u);
  u16*      w2ffrag = (u16*)(wsb + 1852928u);

  pre_kernel<<<PRE_TOTAL, 256, 0, stream>>>(
      xyz, knn_idx, knn_dist,
      wk, wv, de_w2, wkT2, wvB2, w2frag,
      de_w3, de_b3, bk, bv, w3kp, w3vp, bkb3kp, cbias,
      features, wq, bq, (float*)d_out,
      wo, se_w1, se_w2, wofrag, w1afrag, w1bfrag, w2ffrag);
  fused_kernel<<<NROWS, 256, 0, stream>>>(
      features, (float*)d_out, knn_idx, knn_dist,
      wkT2, wvB2, w2frag, w3kp, w3vp,
      de_w1, de_b1, de_b2, bkb3kp, cbias);
  se_kernel<<<NROWS/16, 256, 0, stream>>>(
      features, wofrag, w1afrag, w1bfrag, w2ffrag,
      bo, se_b1, ln_g, ln_b, se_b2, (float*)d_out);
}

// Round 11
// 236.128 us; speedup vs baseline: 1.0103x; 1.0103x over previous
//
#include <hip/hip_runtime.h>
#include <hip/hip_bf16.h>
#include <hip/hip_fp16.h>

#define NPOINTS 2048
#define BATCH   2
#define DIM     256
#define D2      128
#define D4      64
#define NHEAD   8
#define HDIM    32
#define KNNK    64
#define NROWS   (BATCH*NPOINTS)
#define SCALE_F 0.17677669529663687f

// pre_kernel block ranges
#define PRE_PREP   1568
#define PRE_PREP2  (PRE_PREP + 129)
#define PRE_QPROJ  (PRE_PREP2 + 256)
#define PRE_TOTAL  (PRE_QPROJ + NROWS)

typedef unsigned short u16;
typedef _Float16 f16x8 __attribute__((ext_vector_type(8)));
typedef float f32x4 __attribute__((ext_vector_type(4)));

__device__ __forceinline__ u16 f2h(float f) {
  __half h = __float2half(f); u16 r; __builtin_memcpy(&r, &h, 2); return r;
}
__device__ __forceinline__ unsigned pkh2(float a, float b) {
  __half2 h = __floats2half2_rn(a, b); unsigned r; __builtin_memcpy(&r, &h, 4); return r;
}
__device__ __forceinline__ float2 uph2(unsigned u) {
  __half2 h; __builtin_memcpy(&h, &u, 4); return __half22float2(h);
}

#if __has_builtin(__builtin_amdgcn_fdot2)
typedef _Float16 hv2_t __attribute__((ext_vector_type(2)));
__device__ __forceinline__ float fdot2f(unsigned a, unsigned b, float c) {
  hv2_t x, y; __builtin_memcpy(&x, &a, 4); __builtin_memcpy(&y, &b, 4);
  return __builtin_amdgcn_fdot2(x, y, c, false);
}
#else
__device__ __forceinline__ float fdot2f(unsigned a, unsigned b, float c) {
  float2 x = uph2(a), y = uph2(b);
  return fmaf(x.x, y.x, fmaf(x.y, y.y, c));
}
#endif

// MFMA helper: acc[4] (+)= A(16x256 f32 rows in LDS, stride ldsA) @ Bfrag,
// wave w owns n-tiles 4w..4w+3.  Fragment scheme identical to the verified
// h2-GEMM: A lane l holds A[m=l&15][k=ks*32+(l>>4)*8+e]; B packed with the
// same (l,e)->k bijection; D: col=lane&15, row=(lane>>4)*4+reg.
__device__ __forceinline__ void mfma_gemm_acc(
    const float* A, int ldsA, const u16* __restrict__ bfrag,
    int w, int l, f32x4 acc[4])
{
  const int lm = l & 15, lg = l >> 4;
  #pragma unroll
  for (int ks = 0; ks < 8; ++ks) {
    const float* ar = A + lm*ldsA + ks*32 + lg*8;
    float4 a0 = *(const float4*)ar;
    float4 a1 = *(const float4*)(ar + 4);
    f16x8 af;
    af[0]=(_Float16)a0.x; af[1]=(_Float16)a0.y; af[2]=(_Float16)a0.z; af[3]=(_Float16)a0.w;
    af[4]=(_Float16)a1.x; af[5]=(_Float16)a1.y; af[6]=(_Float16)a1.z; af[7]=(_Float16)a1.w;
    #pragma unroll
    for (int ni = 0; ni < 4; ++ni) {
      const int n = w*4 + ni;
      f16x8 bf;
      uint4 bv = *(const uint4*)(bfrag + (((n*8 + ks)*64 + l) << 3));
      __builtin_memcpy(&bf, &bv, 16);
      acc[ni] = __builtin_amdgcn_mfma_f32_16x16x32_f16(af, bf, acc[ni], 0, 0, 0);
    }
  }
}

// ---------------------------------------------------------------------------
// Mega pre-kernel: prep | prep2 | qproj | knn, dispatched by block range.
// ---------------------------------------------------------------------------
__global__ __launch_bounds__(256) void pre_kernel(
    const float* __restrict__ xyz,
    u16*    __restrict__ knn_idx,
    __half* __restrict__ knn_dist,
    const float* __restrict__ wk, const float* __restrict__ wv,
    const float* __restrict__ de_w2,
    u16* __restrict__ wkT2, u16* __restrict__ wvB2, u16* __restrict__ w2frag,
    const float* __restrict__ de_w3, const float* __restrict__ de_b3,
    const float* __restrict__ bk, const float* __restrict__ bv,
    u16* __restrict__ w3kp, u16* __restrict__ w3vp,
    unsigned* __restrict__ bkb3kp, float* __restrict__ cbias,
    const float* __restrict__ features, const float* __restrict__ wq,
    const float* __restrict__ bq, float* __restrict__ qout,
    const float* __restrict__ wo, const float* __restrict__ se_w1,
    const float* __restrict__ se_w2,
    u16* __restrict__ wofrag, u16* __restrict__ w1afrag,
    u16* __restrict__ w1bfrag, u16* __restrict__ w2ffrag)
{
  __shared__ __align__(16) char pmem[16648];
  const int blk = blockIdx.x;
  const int t = threadIdx.x;

  if (blk < PRE_PREP) {
    // ---------------- prep: f16 repacks + MFMA fragment packs ----------------
    int tid = blk*256 + t;
    if (tid < 65536) {
      int d = tid >> 8, c = tid & 255;
      wkT2[(d>>1)*512 + c*2 + (d&1)] = f2h(wk[c*DIM + d]);
    } else if (tid < 131072) {
      int o = tid - 65536; int c = o >> 8, d = o & 255;
      wvB2[(c>>1)*512 + d*2 + (c&1)] = f2h(wv[c*DIM + d]);
    } else if (tid < 139264) {
      int o = tid - 131072;
      int e = o & 7, l = (o >> 3) & 63, ks = (o >> 9) & 1, n = o >> 10;
      int i = ks*32 + ((l >> 4) << 3) + e;
      int j = n*16 + (l & 15);
      w2frag[o] = f2h(de_w2[i*D2 + j]);
    } else if (tid < 401408) {
      int o = (tid - 139264) & 65535;
      int sel = (tid - 139264) >> 16;          // 0:wo 1:w1a 2:w1b 3:w2
      int e = o & 7, l = (o >> 3) & 63, ks = (o >> 9) & 7, n = o >> 12;
      int i = ks*32 + ((l >> 4) << 3) + e;
      int j = n*16 + (l & 15);
      if      (sel == 0) wofrag[o]  = f2h(wo[i*DIM + j]);
      else if (sel == 1) w1afrag[o] = f2h(se_w1[i*DIM + j]);
      else if (sel == 2) w1bfrag[o] = f2h(se_w1[(DIM + i)*DIM + j]);
      else               w2ffrag[o] = f2h(se_w2[i*DIM + j]);
    }
    return;
  }
  if (blk < PRE_PREP2) {
    // ---------------- prep2: weight-fold GEMMs ----------------
    const int j = blk - PRE_PREP;
    float ak = 0.f, av = 0.f;
    if (j < D2) {
      const float* wrow = de_w3 + (size_t)j*DIM;
      #pragma unroll 4
      for (int c = 0; c < DIM; ++c) {
        float w = wrow[c];
        ak = fmaf(w, wk[c*DIM + t], ak);
        av = fmaf(w, wv[c*DIM + t], av);
      }
      w3kp[(((t>>5)*D2 + j)<<5) + (t&31)] = f2h(ak);
      w3vp[(j>>1)*512 + t*2 + (j&1)]      = f2h(av);
    } else {
      #pragma unroll 4
      for (int c = 0; c < DIM; ++c) {
        float w = de_b3[c];
        ak = fmaf(w, wk[c*DIM + t], ak);
        av = fmaf(w, wv[c*DIM + t], av);
      }
      float vb = bk[t] + ak;
      float vbn = __shfl_down(vb, 1);
      if ((t & 1) == 0) bkb3kp[t >> 1] = pkh2(vb, vbn);
      cbias[t] = bv[t] + av;
    }
    return;
  }
  if (blk < PRE_QPROJ) {
    // ---------------- qproj: 16 rows/block; emits q as f16 PAIRS ----------
    float (*sf)[DIM] = (float (*)[DIM])pmem;
    const int r0 = (blk - PRE_PREP2) * 16;
    for (int r = 0; r < 16; ++r) sf[r][t] = features[(size_t)(r0+r)*DIM + t];
    __syncthreads();
    float acc[16];
    const float bqv = bq[t];
    #pragma unroll
    for (int r = 0; r < 16; ++r) acc[r] = bqv;
    for (int d = 0; d < DIM; d += 4) {
      float w0 = wq[(d+0)*DIM+t], w1 = wq[(d+1)*DIM+t];
      float w2 = wq[(d+2)*DIM+t], w3v = wq[(d+3)*DIM+t];
      #pragma unroll
      for (int r = 0; r < 16; ++r) {
        float4 f4 = *(const float4*)&sf[r][d];
        acc[r] = fmaf(f4.x, w0, acc[r]); acc[r] = fmaf(f4.y, w1, acc[r]);
        acc[r] = fmaf(f4.z, w2, acc[r]); acc[r] = fmaf(f4.w, w3v, acc[r]);
      }
    }
    __syncthreads();           // sf (features) dead
    #pragma unroll
    for (int r = 0; r < 16; ++r) sf[r][t] = acc[r];
    __syncthreads();
    if (t < 128) {
      for (int r = 0; r < 16; ++r) {
        unsigned* qpo = (unsigned*)(qout + (size_t)(r0+r)*DIM);
        qpo[t] = pkh2(sf[r][2*t], sf[r][2*t+1]);
      }
    }
    return;
  }

  // ---------------- knn: exact 64-NN on squared distances ----------------
  {
    float*    dist = (float*)pmem;                 // 8KB (squared dists)
    unsigned* hist = (unsigned*)(pmem + 8192);     // 1KB
    unsigned* shw  = (unsigned*)(pmem + 9216);     // sel, below

    const int bp = blk - PRE_QPROJ;
    const int b  = bp >> 11;
    const int n  = bp & (NPOINTS - 1);
    const float* P = xyz + (size_t)b * NPOINTS * 3;

    const float qx = P[n*3+0], qy = P[n*3+1], qz = P[n*3+2];
    const float r2n = qx*qx + qy*qy + qz*qz;
    float dreg[8];
    #pragma unroll
    for (int g = 0; g < 8; ++g) {
      const int m = t + 256*g;
      float x = P[m*3+0], y = P[m*3+1], z = P[m*3+2];
      float r2m = x*x + y*y + z*z;
      float dt  = x*qx + y*qy + z*qz;
      float sq  = r2n + r2m - 2.f*dt;
      dreg[g] = fmaxf(sq, 0.f);     // sqrt deferred to the 64 outputs
      dist[m] = dreg[g];
    }
    __syncthreads();

    unsigned prefix = 0u;
    int k_need = KNNK;
    for (int pass = 0; pass < 4; ++pass) {
      const int shift = 24 - pass*8;
      hist[t] = 0u;
      __syncthreads();
      #pragma unroll
      for (int g = 0; g < 8; ++g) {
        unsigned bits = __float_as_uint(dreg[g]);
        if (((bits >> shift) >> 8) == prefix)
          atomicAdd(&hist[(bits >> shift) & 255u], 1u);
      }
      __syncthreads();
      if (t < 64) {
        unsigned s0 = hist[t*4+0], s1 = hist[t*4+1], s2 = hist[t*4+2], s3 = hist[t*4+3];
        unsigned lsum = s0 + s1 + s2 + s3;
        unsigned scan = lsum;
        #pragma unroll
        for (int off = 1; off < 64; off <<= 1) {
          unsigned o = __shfl_up(scan, off);
          if (t >= off) scan += o;
        }
        unsigned excl = scan - lsum;
        unsigned kk = (unsigned)k_need;
        if (excl < kk && kk <= excl + lsum) {
          unsigned below = excl; int bin = t*4;
          if (kk > below + s0) { below += s0; bin++;
            if (kk > below + s1) { below += s1; bin++;
              if (kk > below + s2) { below += s2; bin++; } } }
          shw[0] = (unsigned)bin; shw[1] = below;
        }
      }
      __syncthreads();
      prefix = (prefix << 8) | shw[0];
      k_need -= (int)shw[1];
      __syncthreads();
    }
    const unsigned Tbits = prefix;
    const int base = KNNK - k_need;

    if (t < 64) {
      u16*    oi = knn_idx  + (size_t)bp * KNNK;
      __half* od = knn_dist + (size_t)bp * KNNK;
      int taken = 0;
      for (int c = 0; c < NPOINTS/64; ++c) {
        int m = c*64 + t;
        float dv = dist[m];
        bool lt = (__float_as_uint(dv) < Tbits);
        unsigned long long msk = __ballot(lt);
        int off = __popcll(msk & ((1ull << t) - 1ull));
        if (lt) { oi[taken+off] = (u16)m; od[taken+off] = __float2half(sqrtf(dv)); }
        taken += __popcll(msk);
      }
      int eq = 0;
      for (int c = 0; c < NPOINTS/64 && eq < k_need; ++c) {
        int m = c*64 + t;
        float dv = dist[m];
        bool e = (__float_as_uint(dv) == Tbits);
        unsigned long long msk = __ballot(e);
        int off = __popcll(msk & ((1ull << t) - 1ull));
        if (e && (eq + off) < k_need) { oi[base+eq+off] = (u16)m; od[base+eq+off] = __float2half(sqrtf(dv)); }
        eq += __popcll(msk);
      }
    }
  }
}

// ---------------------------------------------------------------------------
// Fused per-point pipeline (round-9 form: q via global scalar path, 1-deep
// mF prefetch) + wave-split P8a/mF ordering for pipe balance.
// LDS pool 25120 B -> 6 blocks/CU.
// ---------------------------------------------------------------------------
__global__ __launch_bounds__(256, 6) void fused_kernel(
    const float* __restrict__ features,
    float* __restrict__ qctx,                       // d_out: qp in, ctx out
    const u16*    __restrict__ knn_idx,
    const __half* __restrict__ knn_dist,
    const u16* __restrict__ wkT2, const u16* __restrict__ wvB2,
    const u16* __restrict__ w2frag,
    const u16* __restrict__ w3kp, const u16* __restrict__ w3vp,
    const float* __restrict__ de_w1, const float* __restrict__ de_b1,
    const float* __restrict__ de_b2,
    const unsigned* __restrict__ bkb3kp, const float* __restrict__ cbias)
{
  // [0,16K)        s_h2  h2 f16 swizzled            phase1 -> P8a
  // [16K,20K)      gp u32[8][128] (phase1->P5') | mp u32[8][128] (P8a->P9')
  // [20K,22K)      w3gb f16[8][128] (phase1->P5') | aT f32[64][8] (P6->P8a/mF)
  // [22K,24K)      sc f32[8][64] (P5'->P6)       | ah2p u32[64][8] (P8a->P9')
  // [24K,25120)    nidx[64], ndist[64], sb[8]
  __shared__ __align__(16) char smem[25120];
  unsigned* s_h2_32 = (unsigned*)(smem);
  unsigned* s_gp32  = (unsigned*)(smem + 16384);
  unsigned* s_mp32  = (unsigned*)(smem + 16384);
  u16*      s_w3gb  = (u16*)(smem + 20480);
  unsigned* s_w3g32 = (unsigned*)(smem + 20480);
  float*    s_aT    = (float*)(smem + 20480);
  float*    s_sc    = (float*)(smem + 22528);
  unsigned* s_ah2p  = (unsigned*)(smem + 22528);
  int*      s_nidx  = (int*)(smem + 24576);
  float*    s_ndist = (float*)(smem + 24832);
  float*    s_sb    = (float*)(smem + 25088);

  const int bp = blockIdx.x;
  const int b  = bp >> 11;
  const int t  = threadIdx.x;
  const float* featB = features + (size_t)b * NPOINTS * DIM;
  const unsigned* qp = (const unsigned*)(qctx + (size_t)bp * DIM); // uniform -> s_load

  // ---- P0 ----
  if (t < KNNK) {
    s_nidx[t]  = (int)knn_idx[(size_t)bp*KNNK + t];
    s_ndist[t] = __half2float(knn_dist[(size_t)bp*KNNK + t]);
  }
  __syncthreads();

  // ================= phase 1 =================
  // g-fold: g[c=t][h] = sum_{d in h} wk[c][d] q[d]; linear [h][c] f16 layout.
  {
    const unsigned* wk2 = (const unsigned*)wkT2;
    u16* gps = (u16*)s_gp32;
    #pragma unroll
    for (int h = 0; h < NHEAD; ++h) {
      float a = 0.f;
      #pragma unroll
      for (int dg = 0; dg < 16; ++dg) {
        const int d2 = h*16 + dg;                  // uniform -> scalar loads
        a = fdot2f(wk2[d2*256 + t], qp[d2], a);
      }
      gps[h*256 + t] = f2h(a);
    }
  }
  // w3g-fold: w3g[h][j] = sum_{d in h} w3k[j][d] q[d]; linear [h][j] f16.
  {
    const int h = t >> 5, jj = t & 31;
    unsigned qph[16];
    #pragma unroll
    for (int dp = 0; dp < 16; ++dp) qph[dp] = qp[h*16 + dp];
    const unsigned* w3k32 = (const unsigned*)w3kp;
    #pragma unroll
    for (int r = 0; r < 4; ++r) {
      const int j = jj*4 + r;
      const uint4* wr = (const uint4*)(w3k32 + ((h*D2 + j)<<4));
      uint4 w0 = wr[0], w1 = wr[1], w2 = wr[2], w3 = wr[3];
      float a = 0.f;
      a = fdot2f(w0.x,qph[0],a);  a = fdot2f(w0.y,qph[1],a);
      a = fdot2f(w0.z,qph[2],a);  a = fdot2f(w0.w,qph[3],a);
      a = fdot2f(w1.x,qph[4],a);  a = fdot2f(w1.y,qph[5],a);
      a = fdot2f(w1.z,qph[6],a);  a = fdot2f(w1.w,qph[7],a);
      a = fdot2f(w2.x,qph[8],a);  a = fdot2f(w2.y,qph[9],a);
      a = fdot2f(w2.z,qph[10],a); a = fdot2f(w2.w,qph[11],a);
      a = fdot2f(w3.x,qph[12],a); a = fdot2f(w3.y,qph[13],a);
      a = fdot2f(w3.z,qph[14],a); a = fdot2f(w3.w,qph[15],a);
      s_w3gb[h*D2 + j] = f2h(a);
    }
  }
  if (t < NHEAD) {
    float s = 0.f;
    #pragma unroll
    for (int dp = 0; dp < 16; ++dp)
      s = fdot2f(bkb3kp[t*16 + dp], qp[t*16 + dp], s);
    s_sb[t] = s;
  }
  // h2 = relu(h1 @ w2 + b2) via MFMA; wave w owns n in {2w,2w+1} for all kk.
  {
    const int w = t >> 6, l = t & 63;
    const int lm = l & 15, lg = l >> 4;
    f16x8 af[4][2];
    #pragma unroll
    for (int ks = 0; ks < 2; ++ks) {
      const int i0 = ks*32 + lg*8;
      float4 w1a = *(const float4*)&de_w1[i0];
      float4 w1b = *(const float4*)&de_w1[i0+4];
      float4 b1a = *(const float4*)&de_b1[i0];
      float4 b1b = *(const float4*)&de_b1[i0+4];
      #pragma unroll
      for (int kt = 0; kt < 4; ++kt) {
        const float dd = s_ndist[kt*16 + lm];
        af[kt][ks][0] = (_Float16)fmaxf(fmaf(dd, w1a.x, b1a.x), 0.f);
        af[kt][ks][1] = (_Float16)fmaxf(fmaf(dd, w1a.y, b1a.y), 0.f);
        af[kt][ks][2] = (_Float16)fmaxf(fmaf(dd, w1a.z, b1a.z), 0.f);
        af[kt][ks][3] = (_Float16)fmaxf(fmaf(dd, w1a.w, b1a.w), 0.f);
        af[kt][ks][4] = (_Float16)fmaxf(fmaf(dd, w1b.x, b1b.x), 0.f);
        af[kt][ks][5] = (_Float16)fmaxf(fmaf(dd, w1b.y, b1b.y), 0.f);
        af[kt][ks][6] = (_Float16)fmaxf(fmaf(dd, w1b.z, b1b.z), 0.f);
        af[kt][ks][7] = (_Float16)fmaxf(fmaf(dd, w1b.w, b1b.w), 0.f);
      }
    }
    u16* h2w = (u16*)s_h2_32;
    #pragma unroll
    for (int ni = 0; ni < 2; ++ni) {
      const int n = 2*w + ni;
      const int j = n*16 + lm;
      f16x8 bf0, bf1;
      uint4 r0 = *(const uint4*)(w2frag + (((n*2+0)*64 + l)<<3));
      uint4 r1 = *(const uint4*)(w2frag + (((n*2+1)*64 + l)<<3));
      __builtin_memcpy(&bf0, &r0, 16);
      __builtin_memcpy(&bf1, &r1, 16);
      const float b2j = de_b2[j];
      #pragma unroll
      for (int kt = 0; kt < 4; ++kt) {
        f32x4 c = {b2j, b2j, b2j, b2j};
        c = __builtin_amdgcn_mfma_f32_16x16x32_f16(af[kt][0], bf0, c, 0, 0, 0);
        c = __builtin_amdgcn_mfma_f32_16x16x32_f16(af[kt][1], bf1, c, 0, 0, 0);
        #pragma unroll
        for (int r = 0; r < 4; ++r) {
          const int kk = kt*16 + lg*4 + r;
          h2w[kk*128 + (((j>>3)^(kk&15))<<3) + (j&7)] = f2h(fmaxf(c[r], 0.f));
        }
      }
    }
  }
  __syncthreads();

  // ================= P5': scores =================
  {
    const int kk = t >> 2, sub = t & 3;
    const int kb = kk & 15;
    const float* Fr = featB + (size_t)s_nidx[kk]*DIM;
    float part[8];
    #pragma unroll
    for (int h = 0; h < 8; ++h) part[h] = 0.f;
    #pragma unroll 2
    for (int j = 0; j < 8; ++j) {
      const int c0 = (j*4 + sub)*8;
      float4 fA = *(const float4*)&Fr[c0];
      float4 fB = *(const float4*)&Fr[c0+4];
      unsigned p0 = pkh2(fA.x, fA.y), p1 = pkh2(fA.z, fA.w);
      unsigned p2 = pkh2(fB.x, fB.y), p3 = pkh2(fB.z, fB.w);
      #pragma unroll
      for (int h = 0; h < 8; ++h) {
        uint4 g = *(const uint4*)(s_gp32 + h*128 + (j*4 + sub)*4);
        float a = part[h];
        a = fdot2f(p0, g.x, a); a = fdot2f(p1, g.y, a);
        a = fdot2f(p2, g.z, a); a = fdot2f(p3, g.w, a);
        part[h] = a;
      }
    }
    uint4 h2v[4];
    #pragma unroll
    for (int i = 0; i < 4; ++i)
      h2v[i] = *(const uint4*)(s_h2_32 + kk*64 + ((((sub<<2)+i) ^ kb) << 2));
    #pragma unroll
    for (int h = 0; h < 8; ++h) {
      const uint4* wg = (const uint4*)(s_w3g32 + h*64 + sub*16);
      float a = part[h];
      #pragma unroll
      for (int i = 0; i < 4; ++i) {
        uint4 w = wg[i];
        a = fdot2f(h2v[i].x, w.x, a); a = fdot2f(h2v[i].y, w.y, a);
        a = fdot2f(h2v[i].z, w.z, a); a = fdot2f(h2v[i].w, w.w, a);
      }
      part[h] = a;
    }
    #pragma unroll
    for (int h = 0; h < 8; ++h) {
      part[h] += __shfl_xor(part[h], 1);
      part[h] += __shfl_xor(part[h], 2);
    }
    const int h0 = sub*2;
    s_sc[h0*64 + kk]     = (part[h0]   + s_sb[h0])   * SCALE_F;
    s_sc[(h0+1)*64 + kk] = (part[h0+1] + s_sb[h0+1]) * SCALE_F;
  }
  __syncthreads();

  // ================= P6: softmax =================
  // reads sc [22K,24K); writes aT [20K,22K) over dead w3gb -> disjoint, safe
  {
    const int h = t >> 5, k2 = t & 31;
    float v0 = s_sc[h*64 + k2], v1 = s_sc[h*64 + k2 + 32];
    float mx = fmaxf(v0, v1);
    #pragma unroll
    for (int off = 16; off > 0; off >>= 1) mx = fmaxf(mx, __shfl_xor(mx, off, 32));
    float e0 = expf(v0 - mx), e1 = expf(v1 - mx);
    float sm = e0 + e1;
    #pragma unroll
    for (int off = 16; off > 0; off >>= 1) sm += __shfl_xor(sm, off, 32);
    float inv = 1.f / sm;
    s_aT[k2*NHEAD + h]      = e0 * inv;
    s_aT[(k2+32)*NHEAD + h] = e1 * inv;
  }
  __syncthreads();

  // ================= P8a/mF (wave-split order for pipe balance) ==========
  // Waves 0-1: mF (global-heavy) first, then ah2 (LDS-heavy).
  // Waves 2-3: ah2 first, then mF.  Disjoint LDS writes; both read s_aT.
  {
    const int w = t >> 6, l = t & 63;
    const bool mf_first = (w < 2);
    #pragma unroll
    for (int pass = 0; pass < 2; ++pass) {
      if ((pass == 0) == mf_first) {
        // ---- mF c-split per wave; 1-deep prefetch ----
        const int h = l >> 3, c8 = l & 7;
        const int coff = w*64 + c8*8;
        float mac[8];
        #pragma unroll
        for (int i = 0; i < 8; ++i) mac[i] = 0.f;
        const float* F0 = featB + (size_t)s_nidx[0]*DIM + coff;
        float4 fa = *(const float4*)F0, fb = *(const float4*)(F0+4);
        #pragma unroll 2
        for (int kk = 0; kk < KNNK; ++kk) {
          float4 ca = fa, cbv = fb;
          if (kk < KNNK-1) {
            const float* Fn = featB + (size_t)s_nidx[kk+1]*DIM + coff;
            fa = *(const float4*)Fn; fb = *(const float4*)(Fn+4);
          }
          float a = s_aT[kk*NHEAD + h];
          mac[0] = fmaf(a, ca.x, mac[0]); mac[1] = fmaf(a, ca.y, mac[1]);
          mac[2] = fmaf(a, ca.z, mac[2]); mac[3] = fmaf(a, ca.w, mac[3]);
          mac[4] = fmaf(a, cbv.x, mac[4]); mac[5] = fmaf(a, cbv.y, mac[5]);
          mac[6] = fmaf(a, cbv.z, mac[6]); mac[7] = fmaf(a, cbv.w, mac[7]);
        }
        *(uint4*)(s_mp32 + h*128 + (coff >> 1)) =
            make_uint4(pkh2(mac[0], mac[1]), pkh2(mac[2], mac[3]),
                       pkh2(mac[4], mac[5]), pkh2(mac[6], mac[7]));
      } else {
        // ---- ah2 = attn @ h2, packed f16 j-pairs [j2][h] ----
        const int jj2 = l | ((w & 1) ? 0 : 0);   // l spans 0..63 per wave
        const int hp = w & 1 ? 1 : 0;
        // each wave covers hp in {0,1} x 64 jj2?  Need full (jj2, hp=0..3)
        // over 4 waves: use original mapping (t-based) instead:
        const int jj2b = t & 63, hpb = t >> 6;
        const int j = jj2b*2;
        float a00=0.f, a01=0.f, a10=0.f, a11=0.f;
        #pragma unroll 4
        for (int kk = 0; kk < KNNK; ++kk) {
          unsigned hpw = s_h2_32[kk*64 + (((j>>3)^(kk&15))<<2) + ((j&7)>>1)];
          float2 hv = uph2(hpw);
          float2 av = *(const float2*)&s_aT[kk*NHEAD + hpb*2];
          a00 = fmaf(av.x, hv.x, a00); a01 = fmaf(av.x, hv.y, a01);
          a10 = fmaf(av.y, hv.x, a10); a11 = fmaf(av.y, hv.y, a11);
        }
        s_ah2p[jj2b*8 + hpb*2]     = pkh2(a00, a01);
        s_ah2p[jj2b*8 + hpb*2 + 1] = pkh2(a10, a11);
        (void)jj2; (void)hp;
      }
    }
  }
  __syncthreads();

  // ================= P9': ctx = mF.wv + ah2.w3v + cb (all fdot2) ==========
  {
    const int h = t >> 5;
    const unsigned* mr = s_mp32 + h*128;
    const unsigned* wv32 = (const unsigned*)wvB2;
    float acc = cbias[t];
    #pragma unroll 4
    for (int c2 = 0; c2 < 128; ++c2)
      acc = fdot2f(mr[c2], wv32[c2*256 + t], acc);
    const unsigned* w3v32 = (const unsigned*)w3vp;
    #pragma unroll 4
    for (int j2 = 0; j2 < 64; ++j2)
      acc = fdot2f(s_ah2p[j2*8 + h], w3v32[j2*256 + t], acc);
    qctx[(size_t)bp*DIM + t] = acc;
  }
}

// ---------------------------------------------------------------------------
// Batched tail on MFMA: 16 rows/block, 4 GEMMs via prepacked B-fragments.
// ---------------------------------------------------------------------------
__global__ __launch_bounds__(256) void se_kernel(
    const float* __restrict__ features,
    const u16* __restrict__ wofrag,  const u16* __restrict__ w1afrag,
    const u16* __restrict__ w1bfrag, const u16* __restrict__ w2ffrag,
    const float* __restrict__ bo,    const float* __restrict__ se_b1,
    const float* __restrict__ ln_g,  const float* __restrict__ ln_b,
    const float* __restrict__ se_b2,
    float* io)
{
  __shared__ __align__(16) float sC[16][260];   // ctx -> x
  __shared__ __align__(16) float sF[16][260];   // feat -> rx
  __shared__ __align__(16) float sX[16][260];   // att
  __shared__ float s_mu[16], s_rs[16];
  const int r0 = blockIdx.x * 16, t = threadIdx.x;
  const int w = t >> 6, l = t & 63, lm = l & 15, lg = l >> 4;

  for (int r = 0; r < 16; ++r) {
    sC[r][t] = io[(size_t)(r0+r)*DIM + t];
    sF[r][t] = features[(size_t)(r0+r)*DIM + t];
  }
  __syncthreads();

  // GEMM1: att = ctx @ wo + bo -> sX
  {
    f32x4 acc[4];
    #pragma unroll
    for (int ni = 0; ni < 4; ++ni) {
      float bb = bo[(w*4+ni)*16 + lm];
      acc[ni] = (f32x4){bb, bb, bb, bb};
    }
    mfma_gemm_acc(&sC[0][0], 260, wofrag, w, l, acc);
    #pragma unroll
    for (int ni = 0; ni < 4; ++ni)
      #pragma unroll
      for (int r = 0; r < 4; ++r)
        sX[lg*4+r][(w*4+ni)*16 + lm] = acc[ni][r];
  }
  __syncthreads();   // sX ready; all sC (ctx) reads complete

  // GEMM2: x = feat@w1a + att@w1b + b1 -> sC
  {
    f32x4 acc[4];
    #pragma unroll
    for (int ni = 0; ni < 4; ++ni) {
      float bb = se_b1[(w*4+ni)*16 + lm];
      acc[ni] = (f32x4){bb, bb, bb, bb};
    }
    mfma_gemm_acc(&sF[0][0], 260, w1afrag, w, l, acc);
    mfma_gemm_acc(&sX[0][0], 260, w1bfrag, w, l, acc);
    #pragma unroll
    for (int ni = 0; ni < 4; ++ni)
      #pragma unroll
      for (int r = 0; r < 4; ++r)
        sC[lg*4+r][(w*4+ni)*16 + lm] = acc[ni][r];
  }
  __syncthreads();

  // LayerNorm stats (4 rows per wave)
  {
    const int lane = t & 63;
    for (int i = 0; i < 4; ++i) {
      const int r = w*4 + i;
      float v0 = sC[r][lane], v1 = sC[r][lane+64];
      float v2 = sC[r][lane+128], v3 = sC[r][lane+192];
      float s1 = v0+v1+v2+v3;
      float s2 = v0*v0 + v1*v1 + v2*v2 + v3*v3;
      #pragma unroll
      for (int off = 32; off > 0; off >>= 1) {
        s1 += __shfl_xor(s1, off);
        s2 += __shfl_xor(s2, off);
      }
      if (lane == 0) {
        float mu = s1 * (1.f/256.f);
        s_mu[r] = mu;
        s_rs[r] = 1.f / sqrtf(s2 * (1.f/256.f) - mu*mu + 1e-5f);
      }
    }
  }
  __syncthreads();

  // rx = relu(LN(x)) -> sF (feat dead)
  {
    const float lg2 = ln_g[t], lb2 = ln_b[t];
    #pragma unroll
    for (int r = 0; r < 16; ++r)
      sF[r][t] = fmaxf(fmaf((sC[r][t] - s_mu[r]) * s_rs[r], lg2, lb2), 0.f);
  }
  __syncthreads();

  // GEMM3: out = rx @ se_w2 + b2 -> io
  {
    f32x4 acc[4];
    #pragma unroll
    for (int ni = 0; ni < 4; ++ni) {
      float bb = se_b2[(w*4+ni)*16 + lm];
      acc[ni] = (f32x4){bb, bb, bb, bb};
    }
    mfma_gemm_acc(&sF[0][0], 260, w2ffrag, w, l, acc);
    #pragma unroll
    for (int ni = 0; ni < 4; ++ni)
      #pragma unroll
      for (int r = 0; r < 4; ++r)
        io[(size_t)(r0 + lg*4 + r)*DIM + (w*4+ni)*16 + lm] = acc[ni][r];
  }
}

extern "C" void kernel_launch(void* const* d_in, const int* in_sizes, int n_in,
                              void* d_out, int out_size, void* d_ws, size_t ws_size,
                              hipStream_t stream) {
  const float* features = (const float*)d_in[0];
  const float* xyz      = (const float*)d_in[1];
  const float* de_w1 = (const float*)d_in[2];
  const float* de_b1 = (const float*)d_in[3];
  const float* de_w2 = (const float*)d_in[4];
  const float* de_b2 = (const float*)d_in[5];
  const float* de_w3 = (const float*)d_in[6];
  const float* de_b3 = (const float*)d_in[7];
  const float* wq = (const float*)d_in[8];
  const float* bq = (const float*)d_in[9];
  const float* wk = (const float*)d_in[10];
  const float* bk = (const float*)d_in[11];
  const float* wv = (const float*)d_in[12];
  const float* bv = (const float*)d_in[13];
  const float* wo = (const float*)d_in[14];
  const float* bo = (const float*)d_in[15];
  const float* se_w1 = (const float*)d_in[16];
  const float* se_b1 = (const float*)d_in[17];
  const float* ln_g  = (const float*)d_in[18];
  const float* ln_b  = (const float*)d_in[19];
  const float* se_w2 = (const float*)d_in[20];
  const float* se_b2 = (const float*)d_in[21];

  // ws layout (1984000 B < 2 MB):
  char* wsb = (char*)d_ws;
  u16*    knn_idx  = (u16*)wsb;
  __half* knn_dist = (__half*)(wsb + 524288u);
  u16*      wkT2    = (u16*)(wsb + 1048576u);
  u16*      wvB2    = (u16*)(wsb + 1179648u);
  u16*      w2frag  = (u16*)(wsb + 1310720u);
  u16*      w3kp    = (u16*)(wsb + 1327104u);
  u16*      w3vp    = (u16*)(wsb + 1392640u);
  unsigned* bkb3kp  = (unsigned*)(wsb + 1458176u);
  float*    cbias   = (float*)(wsb + 1458688u);
  u16*      wofrag  = (u16*)(wsb + 1459712u);
  u16*      w1afrag = (u16*)(wsb + 1590784u);
  u16*      w1bfrag = (u16*)(wsb + 1721856u);
  u16*      w2ffrag = (u16*)(wsb + 1852928u);

  pre_kernel<<<PRE_TOTAL, 256, 0, stream>>>(
      xyz, knn_idx, knn_dist,
      wk, wv, de_w2, wkT2, wvB2, w2frag,
      de_w3, de_b3, bk, bv, w3kp, w3vp, bkb3kp, cbias,
      features, wq, bq, (float*)d_out,
      wo, se_w1, se_w2, wofrag, w1afrag, w1bfrag, w2ffrag);
  fused_kernel<<<NROWS, 256, 0, stream>>>(
      features, (float*)d_out, knn_idx, knn_dist,
      wkT2, wvB2, w2frag, w3kp, w3vp,
      de_w1, de_b1, de_b2, bkb3kp, cbias);
  se_kernel<<<NROWS/16, 256, 0, stream>>>(
      features, wofrag, w1afrag, w1bfrag, w2ffrag,
      bo, se_b1, ln_g, ln_b, se_b2, (float*)d_out);
}